// Round 4
// baseline (160.728 us; speedup 1.0000x reference)
//
#include <hip/hip_runtime.h>
#include <math.h>

constexpr int NB = 1024;             // B (samples)
constexpr int NT = 8;                // T
constexpr int NV = 4;                // V
constexpr int ND = 8;                // D
constexpr int M = NB - 4;            // 1020 rows per task
constexpr int NTASK = NV * (NT - 1); // 28 tasks
constexpr int SEGSTEPS = 16;         // k-steps per lane-unit
constexpr int BLK = 512;             // threads per block (8 waves)
constexpr int BLKY = 17;             // 17*512 = 8704 lane-units >= 8256

// ---- ws layout (bytes) ----
// 0      psi[1024] double
// 8192   accum double
// 8200   eps3[NTASK][1020][3] u32   (342720)
// 350920 counts[NTASK][1020] u32    (114240)  -> ends 465160
// 465160 part[NTASK][BLKY][1020][3] u32 (5826240) if ws_size permits

__device__ __forceinline__ int swzS(int r) { return r ^ ((r >> 5) & 7); }
__device__ __forceinline__ int swzM(int r) { return r ^ ((r >> 5) & 31); }

// prefix of seg(h)=ceil((1019-4h)/16)=64-floor((h+1)/4) over h<g, closed form
__device__ __forceinline__ int Ufn(int g) {
  int q = g >> 2, s = g & 3;
  return 64 * g - 2 * q * (q - 1) - (s + 1) * q;
}

__device__ __forceinline__ float cheb8(const float4& a0, const float4& a1,
                                       const float4& b0, const float4& b1) {
  float m0 = fmaxf(fabsf(a0.x - b0.x), fabsf(a0.y - b0.y));
  float m1 = fmaxf(fabsf(a0.z - b0.z), fabsf(a0.w - b0.w));
  float m2 = fmaxf(fabsf(a1.x - b1.x), fabsf(a1.y - b1.y));
  float m3 = fmaxf(fabsf(a1.z - b1.z), fabsf(a1.w - b1.w));
  return fmaxf(fmaxf(m0, m1), fmaxf(m2, m3));
}

// lock-free 3-smallest insert via cascaded atomicMin (works for LDS & global)
template <typename P>
__device__ __forceinline__ void cas3(P* a, unsigned v) {
  unsigned o = atomicMin(a + 0, v); v = v > o ? v : o;
  o = atomicMin(a + 1, v);          v = v > o ? v : o;
  atomicMin(a + 2, v);
}

__global__ void k_init(double* psi, unsigned* eps3, unsigned* counts, double* accum) {
  int gid = blockIdx.x * 256 + threadIdx.x;
  int stride = gridDim.x * 256;
  for (int j = gid; j < NTASK * 1020 * 3; j += stride) eps3[j] = 0xFFFFFFFFu;
  for (int j = gid; j < NTASK * 1020; j += stride) counts[j] = 0u;
  if (gid == 0) *accum = 0.0;
  if (gid >= 1 && gid < NB) {
    double x = (double)gid, acc = 0.0;
    while (x < 10.0) { acc -= 1.0 / x; x += 1.0; }
    double inv = 1.0 / x, i2 = inv * inv;
    double ps = log(x) - 0.5 * inv
              - i2 * (1.0 / 12.0 - i2 * (1.0 / 120.0 - i2 * (1.0 / 252.0)));
    psi[gid] = ps + acc;
  }
}

template <int PASS>
__global__ __launch_bounds__(BLK, 4)
void k_pass(const float* __restrict__ x, unsigned* __restrict__ eps3,
            unsigned* __restrict__ counts, unsigned* __restrict__ part) {
  extern __shared__ char ldsraw[];
  float4* S4 = (float4*)ldsraw;                          // [4][1024] f4: Tlo,Thi,Slo,Shi
  unsigned* M3 = (unsigned*)(ldsraw + 65536);            // pass1: [1024][3]
  float* EPSF = (float*)(ldsraw + 65536);                // pass2: [1024]
  unsigned* CNT = (unsigned*)(ldsraw + 65536 + 4096);    // pass2: [1024]

  const int task = blockIdx.x;
  const int v = task / (NT - 1), ts = 1 + task % (NT - 1);
  const int tid = threadIdx.x;

  // stage both series (swizzled rows)
  const float4* x4 = (const float4*)x;
  for (int idx = tid; idx < 2 * NB; idx += BLK) {
    int ser = idx >> 10, row = idx & 1023;
    int t = ser ? ts : 0;
    int gb = ((row * NT + t) * NV + v) * 2;
    int slot = swzS(row);
    S4[ser * 2048 + slot] = x4[gb];
    S4[ser * 2048 + 1024 + slot] = x4[gb + 1];
  }
  if constexpr (PASS == 1) {
    for (int j = tid; j < 1024 * 3; j += BLK) M3[j] = 0xFFFFFFFFu;
  } else {
    for (int r = tid; r < 1024; r += BLK) {
      int row = swzM(r);
      float e = 0.0f;
      if (row < 1020) {
        const unsigned* g = eps3 + (task * 1020 + row) * 3;
        unsigned m = g[0]; unsigned m1 = g[1]; unsigned m2 = g[2];
        m = m > m1 ? m : m1; m = m > m2 ? m : m2;
        e = __uint_as_float(m);
      }
      EPSF[r] = e;
      CNT[r] = 0u;
    }
  }
  __syncthreads();

  const int u = blockIdx.y * BLK + tid;
  const int U255 = Ufn(255);
  if (u < U255) {
    int G = 0;
    #pragma unroll
    for (int b = 128; b; b >>= 1) {
      int t2 = G + b;
      if (t2 <= 255 && Ufn(t2) <= u) G = t2;
    }
    const int dbase = 4 * G + 1;
    const int LG = 1019 - 4 * G;
    const int k0 = (u - Ufn(G)) * SEGSTEPS;
    const int kend = min(k0 + SEGSTEPS, LG);
    const int kb0 = k0 - 4;

    float uk3[4], pwA[4], pwB[4], pwC[4], vk2[4], qwA[4], qwB[4];
    #pragma unroll
    for (int g = 0; g < 4; ++g) {
      uk3[g] = pwA[g] = pwB[g] = pwC[g] = 0.f;
      vk2[g] = qwA[g] = qwB[g] = 0.f;
    }
    float4 ft[4][2], fs[4][2], nt[2][2], ns[2][2];
    float ef[4];
    // prologue: windows for step kk = kb0 (phi = 0)
    #pragma unroll
    for (int g = 0; g < 4; ++g) {
      int rt = min(k0 + dbase + g, 1023), st = swzS(rt);
      ft[(1 + g) & 3][0] = S4[st]; ft[(1 + g) & 3][1] = S4[1024 + st];
      int rs = min(max(k0 - 1 + dbase + g, 0), 1023), ss = swzS(rs);
      fs[g & 3][0] = S4[2048 + ss]; fs[g & 3][1] = S4[3072 + ss];
      if constexpr (PASS == 2) {
        int re = min(max(kb0 + dbase + g, 0), 1023);
        ef[(1 + g) & 3] = EPSF[swzM(re)];
      }
    }
    {
      int rt = min(k0, 1023), st = swzS(rt);
      nt[0][0] = S4[st]; nt[0][1] = S4[1024 + st];
      int rs = min(max(k0 - 1, 0), 1023), ss = swzS(rs);
      ns[0][0] = S4[2048 + ss]; ns[0][1] = S4[3072 + ss];
    }

    #pragma unroll 1
    for (int it = 0; it < (SEGSTEPS + 4) / 4; ++it) {
      #pragma unroll
      for (int phi = 0; phi < 4; ++phi) {
        const int kk = kb0 + it * 4 + phi;
        float u4[4], v3[4];
        u4[0] = cheb8(nt[phi & 1][0], nt[phi & 1][1],
                      ft[(phi + 1) & 3][0], ft[(phi + 1) & 3][1]);
        v3[0] = cheb8(ns[phi & 1][0], ns[phi & 1][1],
                      fs[phi & 3][0], fs[phi & 3][1]);
        // preloads for next step (overwrite just-consumed slots)
        {
          int r1 = min(kk + dbase + 8, 1023), s1 = swzS(r1);
          ft[(phi + 1) & 3][0] = S4[s1]; ft[(phi + 1) & 3][1] = S4[1024 + s1];
          int r2 = min(kk + dbase + 7, 1023), s2 = swzS(r2);
          fs[phi & 3][0] = S4[2048 + s2]; fs[phi & 3][1] = S4[3072 + s2];
          int r3 = min(kk + 5, 1023), s3 = swzS(r3);
          nt[(phi + 1) & 1][0] = S4[s3]; nt[(phi + 1) & 1][1] = S4[1024 + s3];
          int r4 = min(max(kk + 4, 0), 1023), s4 = swzS(r4);
          ns[(phi + 1) & 1][0] = S4[2048 + s4]; ns[(phi + 1) & 1][1] = S4[3072 + s4];
        }
        float efn = 0.f;
        if constexpr (PASS == 2)
          efn = EPSF[swzM(min(max(kk + dbase + 4, 0), 1023))];
        #pragma unroll
        for (int g = 1; g < 4; ++g) {
          u4[g] = cheb8(nt[phi & 1][0], nt[phi & 1][1],
                        ft[(phi + 1 + g) & 3][0], ft[(phi + 1 + g) & 3][1]);
          v3[g] = cheb8(ns[phi & 1][0], ns[phi & 1][1],
                        fs[(phi + g) & 3][0], fs[(phi + g) & 3][1]);
        }
        const bool vb = (kk >= k0) & (kk < kend);
        const int rN = max(kk, 0);
        const int mN = swzM(rN);
        float eN = 0.f;
        unsigned accN = 0;
        unsigned thrN = 0u;
        if constexpr (PASS == 2) eN = EPSF[mN];
        else thrN = M3[mN * 3 + 2];
        #pragma unroll
        for (int g = 0; g < 4; ++g) {
          float pw3 = fmaxf(uk3[g], u4[g]);
          float dC  = fmaxf(pwA[g], pwC[g]);
          float dAC = fmaxf(dC, u4[g]);
          float qw2 = fmaxf(vk2[g], v3[g]);
          float dB  = fmaxf(qwA[g], qw2);
          float dBC = fmaxf(dB, dC);
          float dJ  = fmaxf(dAC, dB);
          pwA[g] = pwB[g]; pwB[g] = pwC[g]; pwC[g] = pw3; uk3[g] = u4[g];
          qwA[g] = qwB[g]; qwB[g] = qw2; vk2[g] = v3[g];
          const bool mg = vb & (kk + dbase + g <= 1019);
          const int rF = min(max(kk + dbase + g, 0), 1019);
          const int mF = swzM(rF);
          if constexpr (PASS == 1) {
            if (mg) {
              unsigned dm = __float_as_uint(dJ);
              if (dm < thrN) {            // monotone threshold: safe to skip
                cas3(M3 + mN * 3, dm);
                thrN = M3[mN * 3 + 2];
              }
              unsigned thrF = M3[mF * 3 + 2];
              if (dm < thrF) cas3(M3 + mF * 3, dm);
            }
          } else {
            if (mg) {
              float eF = ef[(phi + 1 + g) & 3];
              unsigned pN = (unsigned)(dAC < eN) | ((unsigned)(dBC < eN) << 10)
                          | ((unsigned)(dC < eN) << 20);
              unsigned pF = (unsigned)(dAC < eF) | ((unsigned)(dBC < eF) << 10)
                          | ((unsigned)(dC < eF) << 20);
              accN += pN;
              if (pF) atomicAdd(&CNT[mF], pF);
            }
          }
        }
        if constexpr (PASS == 2) {
          if (accN) atomicAdd(&CNT[mN], accN);
          ef[(phi + 1) & 3] = efn;
        }
      }
    }
  }
  __syncthreads();

  if constexpr (PASS == 1) {
    if (part) {
      // write per-block partial triples; merged by k_emerge (no atomics)
      for (int r = tid; r < 1024; r += BLK) {
        int row = swzM(r);
        if (row < 1020) {
          unsigned* p = part + ((size_t)(task * BLKY + blockIdx.y) * 1020 + row) * 3;
          p[0] = M3[r * 3 + 0]; p[1] = M3[r * 3 + 1]; p[2] = M3[r * 3 + 2];
        }
      }
    } else {
      for (int r = tid; r < 1024; r += BLK) {
        int row = swzM(r);
        if (row < 1020) {
          unsigned* g = eps3 + (task * 1020 + row) * 3;
          unsigned thr = g[2];   // stale-safe guard
          #pragma unroll
          for (int sl = 0; sl < 3; ++sl) {
            unsigned vv = M3[r * 3 + sl];
            if (vv < thr) cas3(g, vv);
          }
        }
      }
    }
  } else {
    for (int r = tid; r < 1024; r += BLK) {
      int row = swzM(r);
      if (row < 1020) {
        unsigned vv = CNT[r];
        if (vv) atomicAdd(&counts[task * 1020 + row], vv);
      }
    }
  }
}

__global__ void k_emerge(const unsigned* __restrict__ part, unsigned* __restrict__ eps3) {
  int gid = blockIdx.x * 256 + threadIdx.x;
  if (gid >= NTASK * 1020) return;
  int task = gid / 1020, row = gid - task * 1020;
  unsigned m0 = 0xFFFFFFFFu, m1 = 0xFFFFFFFFu, m2 = 0xFFFFFFFFu;
  for (int y = 0; y < BLKY; ++y) {
    const unsigned* p = part + ((size_t)(task * BLKY + y) * 1020 + row) * 3;
    #pragma unroll
    for (int sl = 0; sl < 3; ++sl) {
      unsigned vv = p[sl];
      unsigned l0 = min(m0, vv), h0 = max(m0, vv); m0 = l0;
      unsigned l1 = min(m1, h0), h1 = max(m1, h0); m1 = l1;
      m2 = min(m2, h1);
    }
  }
  unsigned* g = eps3 + (size_t)gid * 3;
  g[0] = m0; g[1] = m1; g[2] = m2;
}

__global__ void k_sum(const unsigned* __restrict__ counts,
                      const double* __restrict__ psi, double* __restrict__ accum) {
  int gid = blockIdx.x * 256 + threadIdx.x;
  double term = 0.0;
  if (gid < NTASK * 1020) {
    unsigned p = counts[gid];
    int n0 = p & 1023, n1 = (p >> 10) & 1023, n2 = p >> 20;
    term = psi[n2 + 1] - psi[n0 + 1] - psi[n1 + 1];
  }
  #pragma unroll
  for (int off = 32; off > 0; off >>= 1) term += __shfl_down(term, off);
  if ((threadIdx.x & 63) == 0) atomicAdd(accum, term);
}

__global__ void k_fin(const double* __restrict__ psi, const double* __restrict__ accum,
                      float* __restrict__ out) {
  if (threadIdx.x == 0 && blockIdx.x == 0) {
    double total = (double)NTASK * psi[3] + accum[0] / (double)M;
    double scale = 0.1 / (double)(NT * NV * ND) / (double)NV;
    out[0] = (float)(scale * total);
  }
}

extern "C" void kernel_launch(void* const* d_in, const int* in_sizes, int n_in,
                              void* d_out, int out_size, void* d_ws, size_t ws_size,
                              hipStream_t stream) {
  const float* x = (const float*)d_in[0];
  double* psi = (double*)d_ws;
  double* accum = psi + 1024;
  unsigned* eps3 = (unsigned*)((char*)d_ws + 8200);
  unsigned* counts = eps3 + NTASK * 1020 * 3;
  float* out = (float*)d_out;

  // partial-triple buffer (5,826,240 B) if workspace allows; else atomic merge
  const size_t part_off = 465160;
  const size_t part_bytes = (size_t)NTASK * BLKY * 1020 * 3 * 4;
  unsigned* part = (ws_size >= part_off + part_bytes + 64)
                 ? (unsigned*)((char*)d_ws + part_off) : nullptr;

  (void)hipFuncSetAttribute(reinterpret_cast<const void*>(&k_pass<1>),
                            hipFuncAttributeMaxDynamicSharedMemorySize, 77824);
  (void)hipFuncSetAttribute(reinterpret_cast<const void*>(&k_pass<2>),
                            hipFuncAttributeMaxDynamicSharedMemorySize, 77824);

  hipLaunchKernelGGL(k_init, dim3(120), dim3(256), 0, stream, psi, eps3, counts, accum);
  hipLaunchKernelGGL(HIP_KERNEL_NAME(k_pass<1>), dim3(NTASK, BLKY), dim3(BLK), 77824,
                     stream, x, eps3, counts, part);
  if (part)
    hipLaunchKernelGGL(k_emerge, dim3(112), dim3(256), 0, stream, part, eps3);
  hipLaunchKernelGGL(HIP_KERNEL_NAME(k_pass<2>), dim3(NTASK, BLKY), dim3(BLK), 77824,
                     stream, x, eps3, counts, part);
  hipLaunchKernelGGL(k_sum, dim3(112), dim3(256), 0, stream, counts, psi, accum);
  hipLaunchKernelGGL(k_fin, dim3(1), dim3(1), 0, stream, psi, accum, out);
}

// Round 5
// 131.430 us; speedup vs baseline: 1.2229x; 1.2229x over previous
//
#include <hip/hip_runtime.h>
#include <math.h>

constexpr int NB = 1024;             // B (samples)
constexpr int NT = 8;                // T
constexpr int NV = 4;                // V
constexpr int ND = 8;                // D
constexpr int M = NB - 4;            // 1020 rows per task
constexpr int NTASK = NV * (NT - 1); // 28 tasks
constexpr int SEGSTEPS = 16;         // k-steps per lane-unit
constexpr int BLK = 512;             // threads per block (8 waves)
constexpr int BLKY = 17;             // 17*512 = 8704 lane-units >= 8256

// ---- ws layout (bytes) ----
// 0      psi[1024] double
// 8192   accum double
// 8200   eps3[NTASK][1020][3] u32   (342720)
// 350920 counts[NTASK][1020] u32    (114240)  -> ends 465160
// 465160 part[NTASK][BLKY][1020][3] u32 (5826240) if ws_size permits

__device__ __forceinline__ int swzS(int r) { return r ^ ((r >> 5) & 7); }
__device__ __forceinline__ int swzM(int r) { return r ^ ((r >> 5) & 31); }

// prefix of seg(h)=ceil((1019-4h)/16)=64-floor((h+1)/4) over h<g, closed form
__device__ __forceinline__ int Ufn(int g) {
  int q = g >> 2, s = g & 3;
  return 64 * g - 2 * q * (q - 1) - (s + 1) * q;
}

__device__ __forceinline__ float cheb8(const float4& a0, const float4& a1,
                                       const float4& b0, const float4& b1) {
  float m0 = fmaxf(fabsf(a0.x - b0.x), fabsf(a0.y - b0.y));
  float m1 = fmaxf(fabsf(a0.z - b0.z), fabsf(a0.w - b0.w));
  float m2 = fmaxf(fabsf(a1.x - b1.x), fabsf(a1.y - b1.y));
  float m3 = fmaxf(fabsf(a1.z - b1.z), fabsf(a1.w - b1.w));
  return fmaxf(fmaxf(m0, m1), fmaxf(m2, m3));
}

// lock-free 3-smallest insert via cascaded atomicMin (works for LDS & global)
template <typename P>
__device__ __forceinline__ void cas3(P* a, unsigned v) {
  unsigned o = atomicMin(a + 0, v); v = v > o ? v : o;
  o = atomicMin(a + 1, v);          v = v > o ? v : o;
  atomicMin(a + 2, v);
}

__global__ void k_init(double* psi, unsigned* eps3, unsigned* counts, double* accum) {
  int gid = blockIdx.x * 256 + threadIdx.x;
  int stride = gridDim.x * 256;
  for (int j = gid; j < NTASK * 1020 * 3; j += stride) eps3[j] = 0xFFFFFFFFu;
  for (int j = gid; j < NTASK * 1020; j += stride) counts[j] = 0u;
  if (gid == 0) *accum = 0.0;
  if (gid >= 1 && gid < NB) {
    double x = (double)gid, acc = 0.0;
    while (x < 10.0) { acc -= 1.0 / x; x += 1.0; }
    double inv = 1.0 / x, i2 = inv * inv;
    double ps = log(x) - 0.5 * inv
              - i2 * (1.0 / 12.0 - i2 * (1.0 / 120.0 - i2 * (1.0 / 252.0)));
    psi[gid] = ps + acc;
  }
}

// amdgpu_waves_per_eu(2,4): LDS (77.8 KB dyn) caps us at 2 blocks/CU = 4
// waves/EU anyway; max=4 stops regalloc from squeezing VGPRs below 128 and
// spilling the rolling-window state to scratch (r4: 183 MB scratch writes).
template <int PASS>
__global__ __launch_bounds__(BLK) __attribute__((amdgpu_waves_per_eu(2, 4)))
void k_pass(const float* __restrict__ x, unsigned* __restrict__ eps3,
            unsigned* __restrict__ counts, unsigned* __restrict__ part) {
  extern __shared__ char ldsraw[];
  float4* S4 = (float4*)ldsraw;                          // [4][1024] f4: Tlo,Thi,Slo,Shi
  unsigned* M3 = (unsigned*)(ldsraw + 65536);            // pass1: [1024][3]
  float* EPSF = (float*)(ldsraw + 65536);                // pass2: [1024]
  unsigned* CNT = (unsigned*)(ldsraw + 65536 + 4096);    // pass2: [1024]

  const int task = blockIdx.x;
  const int v = task / (NT - 1), ts = 1 + task % (NT - 1);
  const int tid = threadIdx.x;

  // stage both series (swizzled rows)
  const float4* x4 = (const float4*)x;
  for (int idx = tid; idx < 2 * NB; idx += BLK) {
    int ser = idx >> 10, row = idx & 1023;
    int t = ser ? ts : 0;
    int gb = ((row * NT + t) * NV + v) * 2;
    int slot = swzS(row);
    S4[ser * 2048 + slot] = x4[gb];
    S4[ser * 2048 + 1024 + slot] = x4[gb + 1];
  }
  if constexpr (PASS == 1) {
    for (int j = tid; j < 1024 * 3; j += BLK) M3[j] = 0xFFFFFFFFu;
  } else {
    for (int r = tid; r < 1024; r += BLK) {
      int row = swzM(r);
      float e = 0.0f;
      if (row < 1020) {
        const unsigned* g = eps3 + (task * 1020 + row) * 3;
        unsigned m = g[0]; unsigned m1 = g[1]; unsigned m2 = g[2];
        m = m > m1 ? m : m1; m = m > m2 ? m : m2;
        e = __uint_as_float(m);
      }
      EPSF[r] = e;
      CNT[r] = 0u;
    }
  }
  __syncthreads();

  const int u = blockIdx.y * BLK + tid;
  const int U255 = Ufn(255);
  if (u < U255) {
    int G = 0;
    #pragma unroll
    for (int b = 128; b; b >>= 1) {
      int t2 = G + b;
      if (t2 <= 255 && Ufn(t2) <= u) G = t2;
    }
    const int dbase = 4 * G + 1;
    const int LG = 1019 - 4 * G;
    const int k0 = (u - Ufn(G)) * SEGSTEPS;
    const int kend = min(k0 + SEGSTEPS, LG);
    const int kb0 = k0 - 4;

    float uk3[4], pwA[4], pwB[4], pwC[4], vk2[4], qwA[4], qwB[4];
    #pragma unroll
    for (int g = 0; g < 4; ++g) {
      uk3[g] = pwA[g] = pwB[g] = pwC[g] = 0.f;
      vk2[g] = qwA[g] = qwB[g] = 0.f;
    }
    float4 ft[4][2], fs[4][2], nt[2][2], ns[2][2];
    float ef[4];
    // prologue: windows for step kk = kb0 (phi = 0)
    #pragma unroll
    for (int g = 0; g < 4; ++g) {
      int rt = min(k0 + dbase + g, 1023), st = swzS(rt);
      ft[(1 + g) & 3][0] = S4[st]; ft[(1 + g) & 3][1] = S4[1024 + st];
      int rs = min(max(k0 - 1 + dbase + g, 0), 1023), ss = swzS(rs);
      fs[g & 3][0] = S4[2048 + ss]; fs[g & 3][1] = S4[3072 + ss];
      if constexpr (PASS == 2) {
        int re = min(max(kb0 + dbase + g, 0), 1023);
        ef[(1 + g) & 3] = EPSF[swzM(re)];
      }
    }
    {
      int rt = min(k0, 1023), st = swzS(rt);
      nt[0][0] = S4[st]; nt[0][1] = S4[1024 + st];
      int rs = min(max(k0 - 1, 0), 1023), ss = swzS(rs);
      ns[0][0] = S4[2048 + ss]; ns[0][1] = S4[3072 + ss];
    }

    #pragma unroll 1
    for (int it = 0; it < (SEGSTEPS + 4) / 4; ++it) {
      #pragma unroll
      for (int phi = 0; phi < 4; ++phi) {
        const int kk = kb0 + it * 4 + phi;
        float u4[4], v3[4];
        u4[0] = cheb8(nt[phi & 1][0], nt[phi & 1][1],
                      ft[(phi + 1) & 3][0], ft[(phi + 1) & 3][1]);
        v3[0] = cheb8(ns[phi & 1][0], ns[phi & 1][1],
                      fs[phi & 3][0], fs[phi & 3][1]);
        // preloads for next step (overwrite just-consumed slots)
        {
          int r1 = min(kk + dbase + 8, 1023), s1 = swzS(r1);
          ft[(phi + 1) & 3][0] = S4[s1]; ft[(phi + 1) & 3][1] = S4[1024 + s1];
          int r2 = min(kk + dbase + 7, 1023), s2 = swzS(r2);
          fs[phi & 3][0] = S4[2048 + s2]; fs[phi & 3][1] = S4[3072 + s2];
          int r3 = min(kk + 5, 1023), s3 = swzS(r3);
          nt[(phi + 1) & 1][0] = S4[s3]; nt[(phi + 1) & 1][1] = S4[1024 + s3];
          int r4 = min(max(kk + 4, 0), 1023), s4 = swzS(r4);
          ns[(phi + 1) & 1][0] = S4[2048 + s4]; ns[(phi + 1) & 1][1] = S4[3072 + s4];
        }
        float efn = 0.f;
        if constexpr (PASS == 2)
          efn = EPSF[swzM(min(max(kk + dbase + 4, 0), 1023))];
        #pragma unroll
        for (int g = 1; g < 4; ++g) {
          u4[g] = cheb8(nt[phi & 1][0], nt[phi & 1][1],
                        ft[(phi + 1 + g) & 3][0], ft[(phi + 1 + g) & 3][1]);
          v3[g] = cheb8(ns[phi & 1][0], ns[phi & 1][1],
                        fs[(phi + g) & 3][0], fs[(phi + g) & 3][1]);
        }
        const bool vb = (kk >= k0) & (kk < kend);
        const int rN = max(kk, 0);
        const int mN = swzM(rN);
        float eN = 0.f;
        unsigned accN = 0;
        unsigned thrN = 0u;
        if constexpr (PASS == 2) eN = EPSF[mN];
        else thrN = M3[mN * 3 + 2];
        #pragma unroll
        for (int g = 0; g < 4; ++g) {
          float pw3 = fmaxf(uk3[g], u4[g]);
          float dC  = fmaxf(pwA[g], pwC[g]);
          float dAC = fmaxf(dC, u4[g]);
          float qw2 = fmaxf(vk2[g], v3[g]);
          float dB  = fmaxf(qwA[g], qw2);
          float dBC = fmaxf(dB, dC);
          float dJ  = fmaxf(dAC, dB);
          pwA[g] = pwB[g]; pwB[g] = pwC[g]; pwC[g] = pw3; uk3[g] = u4[g];
          qwA[g] = qwB[g]; qwB[g] = qw2; vk2[g] = v3[g];
          const bool mg = vb & (kk + dbase + g <= 1019);
          const int rF = min(max(kk + dbase + g, 0), 1019);
          const int mF = swzM(rF);
          if constexpr (PASS == 1) {
            if (mg) {
              unsigned dm = __float_as_uint(dJ);
              if (dm < thrN) {            // monotone threshold: safe to skip
                cas3(M3 + mN * 3, dm);
                thrN = M3[mN * 3 + 2];
              }
              unsigned thrF = M3[mF * 3 + 2];
              if (dm < thrF) cas3(M3 + mF * 3, dm);
            }
          } else {
            if (mg) {
              float eF = ef[(phi + 1 + g) & 3];
              unsigned pN = (unsigned)(dAC < eN) | ((unsigned)(dBC < eN) << 10)
                          | ((unsigned)(dC < eN) << 20);
              unsigned pF = (unsigned)(dAC < eF) | ((unsigned)(dBC < eF) << 10)
                          | ((unsigned)(dC < eF) << 20);
              accN += pN;
              if (pF) atomicAdd(&CNT[mF], pF);
            }
          }
        }
        if constexpr (PASS == 2) {
          if (accN) atomicAdd(&CNT[mN], accN);
          ef[(phi + 1) & 3] = efn;
        }
      }
    }
  }
  __syncthreads();

  if constexpr (PASS == 1) {
    if (part) {
      // write per-block partial triples; merged by k_emerge (no atomics)
      for (int r = tid; r < 1024; r += BLK) {
        int row = swzM(r);
        if (row < 1020) {
          unsigned* p = part + ((size_t)(task * BLKY + blockIdx.y) * 1020 + row) * 3;
          p[0] = M3[r * 3 + 0]; p[1] = M3[r * 3 + 1]; p[2] = M3[r * 3 + 2];
        }
      }
    } else {
      for (int r = tid; r < 1024; r += BLK) {
        int row = swzM(r);
        if (row < 1020) {
          unsigned* g = eps3 + (task * 1020 + row) * 3;
          unsigned thr = g[2];   // stale-safe guard
          #pragma unroll
          for (int sl = 0; sl < 3; ++sl) {
            unsigned vv = M3[r * 3 + sl];
            if (vv < thr) cas3(g, vv);
          }
        }
      }
    }
  } else {
    for (int r = tid; r < 1024; r += BLK) {
      int row = swzM(r);
      if (row < 1020) {
        unsigned vv = CNT[r];
        if (vv) atomicAdd(&counts[task * 1020 + row], vv);
      }
    }
  }
}

__global__ void k_emerge(const unsigned* __restrict__ part, unsigned* __restrict__ eps3) {
  int gid = blockIdx.x * 256 + threadIdx.x;
  if (gid >= NTASK * 1020) return;
  int task = gid / 1020, row = gid - task * 1020;
  unsigned m0 = 0xFFFFFFFFu, m1 = 0xFFFFFFFFu, m2 = 0xFFFFFFFFu;
  for (int y = 0; y < BLKY; ++y) {
    const unsigned* p = part + ((size_t)(task * BLKY + y) * 1020 + row) * 3;
    #pragma unroll
    for (int sl = 0; sl < 3; ++sl) {
      unsigned vv = p[sl];
      unsigned l0 = min(m0, vv), h0 = max(m0, vv); m0 = l0;
      unsigned l1 = min(m1, h0), h1 = max(m1, h0); m1 = l1;
      m2 = min(m2, h1);
    }
  }
  unsigned* g = eps3 + (size_t)gid * 3;
  g[0] = m0; g[1] = m1; g[2] = m2;
}

__global__ void k_sum(const unsigned* __restrict__ counts,
                      const double* __restrict__ psi, double* __restrict__ accum) {
  int gid = blockIdx.x * 256 + threadIdx.x;
  double term = 0.0;
  if (gid < NTASK * 1020) {
    unsigned p = counts[gid];
    int n0 = p & 1023, n1 = (p >> 10) & 1023, n2 = p >> 20;
    term = psi[n2 + 1] - psi[n0 + 1] - psi[n1 + 1];
  }
  #pragma unroll
  for (int off = 32; off > 0; off >>= 1) term += __shfl_down(term, off);
  if ((threadIdx.x & 63) == 0) atomicAdd(accum, term);
}

__global__ void k_fin(const double* __restrict__ psi, const double* __restrict__ accum,
                      float* __restrict__ out) {
  if (threadIdx.x == 0 && blockIdx.x == 0) {
    double total = (double)NTASK * psi[3] + accum[0] / (double)M;
    double scale = 0.1 / (double)(NT * NV * ND) / (double)NV;
    out[0] = (float)(scale * total);
  }
}

extern "C" void kernel_launch(void* const* d_in, const int* in_sizes, int n_in,
                              void* d_out, int out_size, void* d_ws, size_t ws_size,
                              hipStream_t stream) {
  const float* x = (const float*)d_in[0];
  double* psi = (double*)d_ws;
  double* accum = psi + 1024;
  unsigned* eps3 = (unsigned*)((char*)d_ws + 8200);
  unsigned* counts = eps3 + NTASK * 1020 * 3;
  float* out = (float*)d_out;

  // partial-triple buffer (5,826,240 B) if workspace allows; else atomic merge
  const size_t part_off = 465160;
  const size_t part_bytes = (size_t)NTASK * BLKY * 1020 * 3 * 4;
  unsigned* part = (ws_size >= part_off + part_bytes + 64)
                 ? (unsigned*)((char*)d_ws + part_off) : nullptr;

  (void)hipFuncSetAttribute(reinterpret_cast<const void*>(&k_pass<1>),
                            hipFuncAttributeMaxDynamicSharedMemorySize, 77824);
  (void)hipFuncSetAttribute(reinterpret_cast<const void*>(&k_pass<2>),
                            hipFuncAttributeMaxDynamicSharedMemorySize, 77824);

  hipLaunchKernelGGL(k_init, dim3(120), dim3(256), 0, stream, psi, eps3, counts, accum);
  hipLaunchKernelGGL(HIP_KERNEL_NAME(k_pass<1>), dim3(NTASK, BLKY), dim3(BLK), 77824,
                     stream, x, eps3, counts, part);
  if (part)
    hipLaunchKernelGGL(k_emerge, dim3(112), dim3(256), 0, stream, part, eps3);
  hipLaunchKernelGGL(HIP_KERNEL_NAME(k_pass<2>), dim3(NTASK, BLKY), dim3(BLK), 77824,
                     stream, x, eps3, counts, part);
  hipLaunchKernelGGL(k_sum, dim3(112), dim3(256), 0, stream, counts, psi, accum);
  hipLaunchKernelGGL(k_fin, dim3(1), dim3(1), 0, stream, psi, accum, out);
}